// Round 19
// baseline (38.728 us; speedup 1.0000x reference)
//
#include <hip/hip_runtime.h>

// PSROI pooling: fsam (N=8, C=245, H=80, W=80) f32, box (R=8192, 5) f32
// out (R, 245) f32. out[r, c] = mean over fsam[b, c, hs:he, ws:we].
//
// ARITHMETIC (frozen since R10, DO NOT TOUCH): bin = roi * fl32(1/7)
// (reciprocal multiply, 0x3E124925) and edges = SEPARATELY-rounded
// g*bin + off (asm barriers). Matches ref (absmax <= 0.016 << 0.0725).
//
// R19: channel-pair blocks. R18's counters: VALUBusy 33% (~14us VALU issue)
// is the largest component; pool edge math is replicated per channel.
// Channels c and c+49 share (ph,pw) -> BIT-IDENTICAL edges. A block now
// builds TWO SATs (ctop, ctop+1 planes of one (ph,pw), same image) in
// 53.8KB LDS and the pool computes edges ONCE per ROI, taps both SATs,
// writes both outputs. Grid 1960 -> 1176 (784 pairs + 392 singles);
// per-block fixed costs amortize 2x; scans for both planes share the same
// 3 barrier phases (640 tasks / 512 threads). R17 bucket kernel restored
// (R18's self-bucket re-scanned 160KB/block - regressed).

#define N_ 8
#define C_ 245
#define H_ 80
#define W_ 80
#define R_ 8192
#define P_ 7
#define SROW 84                    // row stride in floats (21 float4)
#define PLF4 1680                  // float4s per plane SAT (80*21)

// XLA-style separately-rounded a*b + c in f32; barriers forbid contraction.
__device__ __forceinline__ float sep_ma(float a, float b, float c) {
    float p = a * b;                 // v_mul_f32, IEEE RN
    asm volatile("" : "+v"(p));      // contraction barrier
    float s = p + c;                 // v_add_f32, IEEE RN
    asm volatile("" : "+v"(s));
    return s;
}

// ---- kernel 1: deterministic bucket build (8 blocks, no atomics) ----
__global__ __launch_bounds__(256) void bucket_kernel(
    const float* __restrict__ box, int* __restrict__ cnt,
    int* __restrict__ buckets)
{
    __shared__ int psum[256];
    int b = blockIdx.x;                    // image
    int t = threadIdx.x;
    int r0 = t * 32;                       // contiguous range per thread

    unsigned match = 0u;
    int m = 0;
    #pragma unroll
    for (int k = 0; k < 32; ++k) {
        int bb = (int)box[(size_t)(r0 + k) * 5];
        if (bb == b) { match |= 1u << k; ++m; }
    }
    psum[t] = m;
    __syncthreads();

    for (int off = 1; off < 256; off <<= 1) {
        int v = (t >= off) ? psum[t - off] : 0;
        __syncthreads();
        psum[t] += v;
        __syncthreads();
    }
    int pos = psum[t] - m;                 // exclusive prefix
    for (int k = 0; k < 32; ++k)
        if (match & (1u << k)) buckets[b * R_ + pos++] = r0 + k;
    if (t == 255) cnt[b] = psum[255];
}

__device__ __forceinline__ float4 f4_add(float4 a, float4 b) {
    return make_float4(a.x + b.x, a.y + b.y, a.z + b.z, a.w + b.w);
}

// ---- kernel 2: fused dual-SAT-in-LDS + pool, 512 threads ----
__global__ __launch_bounds__(512) void fused_kernel(
    const float* __restrict__ fsam,
    const float* __restrict__ box,
    const int* __restrict__ cnt,
    const int* __restrict__ buckets,
    float* __restrict__ out)
{
    __shared__ float S[2 * H_ * SROW];     // 53760 B (two plane SATs)
    int id  = blockIdx.x;                  // 0..1175
    int b   = id & 7;                      // image (XCD swizzle: XCD = b)
    int hi  = id >> 3;                     // 0..146
    int pq  = hi % 49;                     // (ph,pw) index
    int slot= hi / 49;                     // 0,1 -> pairs; 2 -> single
    int c0  = slot * 98 + pq;              // ctop = 2*slot
    int has2= slot < 2;                    // second plane = c0 + 49
    int tid = threadIdx.x;

    const float* p0 = fsam + ((size_t)b * C_ + c0) * (H_ * W_);
    const float* p1 = p0 + 49 * (H_ * W_);

    // ---- load: 1600 (or 3200) float4, coalesced global -> b128 LDS ----
    int nf4 = has2 ? 3200 : 1600;
    for (int i = tid; i < nf4; i += 512) {
        int pl = i >= 1600;
        int ii = i - (pl << 10) - (pl << 9);         // i - pl*1536... no:
        ii = pl ? i - 1600 : i;
        int row = (int)((unsigned)ii / 20u);
        int c4  = ii - row * 20;
        float4 v = ((const float4*)(pl ? p1 : p0))[ii];
        ((float4*)S)[pl * PLF4 + row * 21 + c4] = v;
    }
    __syncthreads();

    // ---- horizontal scan: (1 or 2 planes) x 80 rows x 4 chunks of 20 ----
    int ntask = has2 ? 640 : 320;
    #pragma unroll
    for (int pass = 0; pass < 2; ++pass) {
        int T = tid + pass * 512;
        if (T < ntask) {
            int pl  = T >= 320;
            int t   = T - pl * 320;
            int row = t >> 2, q = t & 3;
            float4* base = (float4*)S + pl * PLF4 + row * 21 + q * 5;
            float v[20];
            #pragma unroll
            for (int k = 0; k < 5; ++k) {
                float4 x = base[k];
                v[4*k+0] = x.x; v[4*k+1] = x.y; v[4*k+2] = x.z; v[4*k+3] = x.w;
            }
            float run = 0.0f;
            #pragma unroll
            for (int j = 0; j < 20; ++j) { run += v[j]; v[j] = run; }
            float incl = run;
            #pragma unroll
            for (int d = 1; d < 4; d <<= 1) {
                float u = __shfl_up(incl, d, 4);
                if (q >= d) incl += u;
            }
            float off = incl - run;
            #pragma unroll
            for (int j = 0; j < 20; ++j) v[j] += off;
            #pragma unroll
            for (int k = 0; k < 5; ++k)
                base[k] = make_float4(v[4*k+0], v[4*k+1], v[4*k+2], v[4*k+3]);
        }
    }
    __syncthreads();

    // ---- vertical scan: (1 or 2) x 20 col-groups x 16 chunks of 5 ----
    #pragma unroll
    for (int pass = 0; pass < 2; ++pass) {
        int T = tid + pass * 512;
        if (T < ntask) {
            int pl = T >= 320;
            int t  = T - pl * 320;
            int cg = t >> 4;
            int ch = t & 15;
            float4* col = (float4*)S + pl * PLF4 + cg;
            float4 v[5];
            float4 run = make_float4(0.f, 0.f, 0.f, 0.f);
            #pragma unroll
            for (int j = 0; j < 5; ++j) {
                run = f4_add(run, col[(ch * 5 + j) * 21]);
                v[j] = run;
            }
            float4 incl = run;
            #pragma unroll
            for (int d = 1; d < 16; d <<= 1) {
                float4 u;
                u.x = __shfl_up(incl.x, d, 16);
                u.y = __shfl_up(incl.y, d, 16);
                u.z = __shfl_up(incl.z, d, 16);
                u.w = __shfl_up(incl.w, d, 16);
                if (ch >= d) incl = f4_add(incl, u);
            }
            float4 off = make_float4(incl.x - run.x, incl.y - run.y,
                                     incl.z - run.z, incl.w - run.w);
            #pragma unroll
            for (int j = 0; j < 5; ++j)
                col[(ch * 5 + j) * 21] = f4_add(v[j], off);
        }
    }
    __syncthreads();

    // ---- pool: edges ONCE per ROI, tap both SATs ----
    int ph = pq / P_;                      // block-uniform
    int pw = pq % P_;
    int n  = cnt[b];
    const int* lst = buckets + b * R_;

    for (int i = tid; i < n; i += 512) {
        int r = lst[i];
        const float* bx = box + (size_t)r * 5;

        // ---- R10-frozen edge arithmetic ----
        float x1 = rintf(bx[1]);
        float y1 = rintf(bx[2]);
        float x2 = rintf(bx[3] + 1.0f);
        float y2 = rintf(bx[4] + 1.0f);

        float roi_w = fmaxf(x2 - x1, 0.1f);
        float roi_h = fmaxf(y2 - y1, 0.1f);

        const float RCP7 = __uint_as_float(0x3E124925u); // fl32(1/7)
        float bin_w = roi_w * RCP7;
        float bin_h = roi_h * RCP7;
        asm volatile("" : "+v"(bin_w), "+v"(bin_h));

        float hs_f = floorf(sep_ma((float)ph,       bin_h, y1));
        float he_f = ceilf (sep_ma((float)(ph + 1), bin_h, y1));
        float ws_f = floorf(sep_ma((float)pw,       bin_w, x1));
        float we_f = ceilf (sep_ma((float)(pw + 1), bin_w, x1));

        int hs = (int)fminf(fmaxf(hs_f, 0.0f), 80.0f);
        int he = (int)fminf(fmaxf(he_f, 0.0f), 80.0f);
        int ws = (int)fminf(fmaxf(ws_f, 0.0f), 80.0f);
        int we = (int)fminf(fmaxf(we_f, 0.0f), 80.0f);

        int i1 = he > 0 ? he - 1 : 0, i0 = hs > 0 ? hs - 1 : 0;
        int j1 = we > 0 ? we - 1 : 0, j0 = ws > 0 ? ws - 1 : 0;
        bool b11 = (he > 0 && we > 0), b01 = (hs > 0 && we > 0);
        bool b10 = (he > 0 && ws > 0), b00 = (hs > 0 && ws > 0);
        int area = (he - hs) * (we - ws);
        float inv = (area > 0) ? 1.0f : 0.0f;   // area>0 guard; div below

        // plane 0 taps
        {
            float v11 = S[i1 * SROW + j1];
            float v01 = S[i0 * SROW + j1];
            float v10 = S[i1 * SROW + j0];
            float v00 = S[i0 * SROW + j0];
            float t11 = b11 ? v11 : 0.0f;
            float t01 = b01 ? v01 : 0.0f;
            float t10 = b10 ? v10 : 0.0f;
            float t00 = b00 ? v00 : 0.0f;
            float bin_sum = ((t11 - t01) - t10) + t00;
            out[(size_t)r * C_ + c0] =
                (area > 0) ? bin_sum / (float)area : 0.0f;
        }
        // plane 1 taps (same edges, bit-identical by construction)
        if (has2) {
            const float* S1 = S + H_ * SROW;
            float v11 = S1[i1 * SROW + j1];
            float v01 = S1[i0 * SROW + j1];
            float v10 = S1[i1 * SROW + j0];
            float v00 = S1[i0 * SROW + j0];
            float t11 = b11 ? v11 : 0.0f;
            float t01 = b01 ? v01 : 0.0f;
            float t10 = b10 ? v10 : 0.0f;
            float t00 = b00 ? v00 : 0.0f;
            float bin_sum = ((t11 - t01) - t10) + t00;
            out[(size_t)r * C_ + c0 + 49] =
                (area > 0) ? bin_sum / (float)area : 0.0f;
        }
        (void)inv;
    }
}

// ---- fallback: R11 direct-sum kernel (ws too small) ----
__global__ __launch_bounds__(256) void psroi_direct_kernel(
    const float* __restrict__ fsam,
    const float* __restrict__ box,
    float* __restrict__ out)
{
    int id = blockIdx.x;
    int j  = id & 7;
    int m  = id >> 3;
    int g  = (m < 512) ? j : j + 8;
    int l  = (m < 512) ? m : m - 512;
    int c    = g * 16 + (l >> 5);
    int rblk = l & 31;
    if (c >= C_) return;

    int r = rblk * 256 + (int)threadIdx.x;
    int pw = c % P_;
    int ph = (c / P_) % P_;

    const float* bx = box + (size_t)r * 5;
    int   b  = (int)bx[0];
    float x1 = rintf(bx[1]);
    float y1 = rintf(bx[2]);
    float x2 = rintf(bx[3] + 1.0f);
    float y2 = rintf(bx[4] + 1.0f);

    float roi_w = fmaxf(x2 - x1, 0.1f);
    float roi_h = fmaxf(y2 - y1, 0.1f);

    const float RCP7 = __uint_as_float(0x3E124925u);
    float bin_w = roi_w * RCP7;
    float bin_h = roi_h * RCP7;
    asm volatile("" : "+v"(bin_w), "+v"(bin_h));

    float hs_f = floorf(sep_ma((float)ph,       bin_h, y1));
    float he_f = ceilf (sep_ma((float)(ph + 1), bin_h, y1));
    float ws_f = floorf(sep_ma((float)pw,       bin_w, x1));
    float we_f = ceilf (sep_ma((float)(pw + 1), bin_w, x1));

    int hs = (int)fminf(fmaxf(hs_f, 0.0f), 80.0f);
    int he = (int)fminf(fmaxf(he_f, 0.0f), 80.0f);
    int ws = (int)fminf(fmaxf(ws_f, 0.0f), 80.0f);
    int we = (int)fminf(fmaxf(we_f, 0.0f), 80.0f);

    const float* plane = fsam + ((size_t)b * C_ + c) * (H_ * W_);
    float s = 0.0f;
    for (int y = hs; y < he; ++y) {
        const float* row = plane + y * W_;
        for (int x = ws; x < we; ++x) s += row[x];
    }
    int area = (he - hs) * (we - ws);
    out[(size_t)r * C_ + c] = (area > 0) ? s / (float)area : 0.0f;
}

extern "C" void kernel_launch(void* const* d_in, const int* in_sizes, int n_in,
                              void* d_out, int out_size, void* d_ws, size_t ws_size,
                              hipStream_t stream) {
    const float* fsam = (const float*)d_in[0];
    const float* box  = (const float*)d_in[1];
    float* out = (float*)d_out;

    // ws layout: [0,32) counts (8 ints), [32, 32+8*8192*4) buckets
    size_t need = 32 + (size_t)N_ * R_ * sizeof(int);   // 262176 B
    if (ws_size >= need) {
        int* cnt     = (int*)d_ws;
        int* buckets = (int*)((char*)d_ws + 32);
        bucket_kernel<<<N_, 256, 0, stream>>>(box, cnt, buckets);
        fused_kernel<<<8 * 147, 512, 0, stream>>>(fsam, box, cnt, buckets, out);
    } else {
        psroi_direct_kernel<<<8192, 256, 0, stream>>>(fsam, box, out);
    }
}

// Round 20
// 35.331 us; speedup vs baseline: 1.0961x; 1.0961x over previous
//
#include <hip/hip_runtime.h>

// PSROI pooling: fsam (N=8, C=245, H=80, W=80) f32, box (R=8192, 5) f32
// out (R, 245) f32. out[r, c] = mean over fsam[b, c, hs:he, ws:we].
//
// ARITHMETIC (frozen since R10, DO NOT TOUCH): bin = roi * fl32(1/7)
// (reciprocal multiply, 0x3E124925) and edges = SEPARATELY-rounded
// g*bin + off (asm barriers). Matches ref (absmax <= 0.016 << 0.0725).
//
// R20: persistent multi-plane blocks + LDS double-buffer pipeline.
// R15-R19 plateau at ~37-39us while the throughput model says ~10us ->
// latency exposure: phase-lockstep blocks (load|scan|scan|pool separated
// by barriers) at 2.3 blocks/CU effective residency. Now: grid 736 =
// 8 images x 92; block owns 2-3 planes of one image (c = s, s+92, s+184);
// LDS 2x26.9KB (3 blocks/CU, 24 waves); plane k+1's 1600 float4 are
// loaded into REGISTERS right after plane k's first barrier (latency
// hides under k's scans+pool) and ds_written into the other buffer.
// Buffer parity => no extra barrier (3 barriers/plane). Scan + pool +
// bucket + edge arithmetic copied verbatim -> bit-identical output.

#define N_ 8
#define C_ 245
#define H_ 80
#define W_ 80
#define R_ 8192
#define P_ 7
#define SROW 84                    // row stride in floats (21 float4)
#define PLF4 1680                  // float4s per plane buffer (80*21)

// XLA-style separately-rounded a*b + c in f32; barriers forbid contraction.
__device__ __forceinline__ float sep_ma(float a, float b, float c) {
    float p = a * b;                 // v_mul_f32, IEEE RN
    asm volatile("" : "+v"(p));      // contraction barrier
    float s = p + c;                 // v_add_f32, IEEE RN
    asm volatile("" : "+v"(s));
    return s;
}

// ---- kernel 1: deterministic bucket build (8 blocks, no atomics) ----
__global__ __launch_bounds__(256) void bucket_kernel(
    const float* __restrict__ box, int* __restrict__ cnt,
    int* __restrict__ buckets)
{
    __shared__ int psum[256];
    int b = blockIdx.x;                    // image
    int t = threadIdx.x;
    int r0 = t * 32;                       // contiguous range per thread

    unsigned match = 0u;
    int m = 0;
    #pragma unroll
    for (int k = 0; k < 32; ++k) {
        int bb = (int)box[(size_t)(r0 + k) * 5];
        if (bb == b) { match |= 1u << k; ++m; }
    }
    psum[t] = m;
    __syncthreads();

    for (int off = 1; off < 256; off <<= 1) {
        int v = (t >= off) ? psum[t - off] : 0;
        __syncthreads();
        psum[t] += v;
        __syncthreads();
    }
    int pos = psum[t] - m;                 // exclusive prefix
    for (int k = 0; k < 32; ++k)
        if (match & (1u << k)) buckets[b * R_ + pos++] = r0 + k;
    if (t == 255) cnt[b] = psum[255];
}

__device__ __forceinline__ float4 f4_add(float4 a, float4 b) {
    return make_float4(a.x + b.x, a.y + b.y, a.z + b.z, a.w + b.w);
}

// ---- kernel 2: persistent dual-buffer SAT + pool, 512 threads ----
__global__ __launch_bounds__(512) void fused_kernel(
    const float* __restrict__ fsam,
    const float* __restrict__ box,
    const int* __restrict__ cnt,
    const int* __restrict__ buckets,
    float* __restrict__ out)
{
    __shared__ float S[2][H_ * SROW];      // 2 x 26880 B = 53760 B
    int id  = blockIdx.x;                  // 0..735
    int b   = id & 7;                      // image (XCD swizzle: XCD = b)
    int s   = id >> 3;                     // 0..91
    int np  = (s <= 60) ? 3 : 2;           // planes: c = s, s+92, s+184
    int tid = threadIdx.x;

    int n  = cnt[b];
    const int* lst = buckets + b * R_;

    // register staging for one plane (1600 float4 / 512 threads)
    float4 ld0, ld1, ld2, ld3;
    auto do_load = [&](int c) {
        const float4* src = (const float4*)(fsam + ((size_t)b * C_ + c) * (H_ * W_));
        ld0 = src[tid];
        ld1 = src[tid + 512];
        ld2 = src[tid + 1024];
        if (tid < 64) ld3 = src[tid + 1536];
    };
    auto wr1 = [&](float* B, int i, float4 v) {
        int row = (int)((unsigned)i / 20u);
        int c4  = i - row * 20;
        ((float4*)B)[row * 21 + c4] = v;
    };
    auto do_write = [&](float* B) {
        wr1(B, tid,        ld0);
        wr1(B, tid +  512, ld1);
        wr1(B, tid + 1024, ld2);
        if (tid < 64) wr1(B, tid + 1536, ld3);
    };

    do_load(s);                            // prologue: plane 0

    for (int k = 0; k < np; ++k) {
        int c = s + 92 * k;
        float* B = S[k & 1];

        do_write(B);
        __syncthreads();                   // raw plane ready in B

        if (k + 1 < np) do_load(s + 92 * (k + 1));   // hides under scans+pool

        // ---- horizontal scan: 80 rows x 4 chunks of 20, in registers ----
        if (tid < 320) {
            int row = tid >> 2, q = tid & 3;
            float4* base = (float4*)B + row * 21 + q * 5;
            float v[20];
            #pragma unroll
            for (int kk = 0; kk < 5; ++kk) {
                float4 t = base[kk];
                v[4*kk+0] = t.x; v[4*kk+1] = t.y; v[4*kk+2] = t.z; v[4*kk+3] = t.w;
            }
            float run = 0.0f;
            #pragma unroll
            for (int j = 0; j < 20; ++j) { run += v[j]; v[j] = run; }
            float incl = run;
            #pragma unroll
            for (int d = 1; d < 4; d <<= 1) {
                float u = __shfl_up(incl, d, 4);
                if (q >= d) incl += u;
            }
            float off = incl - run;
            #pragma unroll
            for (int j = 0; j < 20; ++j) v[j] += off;
            #pragma unroll
            for (int kk = 0; kk < 5; ++kk)
                base[kk] = make_float4(v[4*kk+0], v[4*kk+1], v[4*kk+2], v[4*kk+3]);
        }
        __syncthreads();

        // ---- vertical scan: 20 col-groups x 16 chunks of 5 rows ----
        if (tid < 320) {
            int cg = tid >> 4;             // 0..19
            int ch = tid & 15;             // 0..15
            float4* col = (float4*)B + cg;
            float4 v[5];
            float4 run = make_float4(0.f, 0.f, 0.f, 0.f);
            #pragma unroll
            for (int j = 0; j < 5; ++j) {
                run = f4_add(run, col[(ch * 5 + j) * 21]);
                v[j] = run;
            }
            float4 incl = run;
            #pragma unroll
            for (int d = 1; d < 16; d <<= 1) {
                float4 u;
                u.x = __shfl_up(incl.x, d, 16);
                u.y = __shfl_up(incl.y, d, 16);
                u.z = __shfl_up(incl.z, d, 16);
                u.w = __shfl_up(incl.w, d, 16);
                if (ch >= d) incl = f4_add(incl, u);
            }
            float4 off = make_float4(incl.x - run.x, incl.y - run.y,
                                     incl.z - run.z, incl.w - run.w);
            #pragma unroll
            for (int j = 0; j < 5; ++j)
                col[(ch * 5 + j) * 21] = f4_add(v[j], off);
        }
        __syncthreads();

        // ---- pool this image's ROIs from SAT in B ----
        int ph = (c / P_) % P_;            // block-uniform
        int pw = c % P_;

        for (int i = tid; i < n; i += 512) {
            int r = lst[i];
            const float* bx = box + (size_t)r * 5;

            // ---- R10-frozen edge arithmetic ----
            float x1 = rintf(bx[1]);
            float y1 = rintf(bx[2]);
            float x2 = rintf(bx[3] + 1.0f);
            float y2 = rintf(bx[4] + 1.0f);

            float roi_w = fmaxf(x2 - x1, 0.1f);
            float roi_h = fmaxf(y2 - y1, 0.1f);

            const float RCP7 = __uint_as_float(0x3E124925u); // fl32(1/7)
            float bin_w = roi_w * RCP7;
            float bin_h = roi_h * RCP7;
            asm volatile("" : "+v"(bin_w), "+v"(bin_h));

            float hs_f = floorf(sep_ma((float)ph,       bin_h, y1));
            float he_f = ceilf (sep_ma((float)(ph + 1), bin_h, y1));
            float ws_f = floorf(sep_ma((float)pw,       bin_w, x1));
            float we_f = ceilf (sep_ma((float)(pw + 1), bin_w, x1));

            int hs = (int)fminf(fmaxf(hs_f, 0.0f), 80.0f);
            int he = (int)fminf(fmaxf(he_f, 0.0f), 80.0f);
            int ws = (int)fminf(fmaxf(ws_f, 0.0f), 80.0f);
            int we = (int)fminf(fmaxf(we_f, 0.0f), 80.0f);

            // SAT taps with implicit zero row/col (clamp + select)
            int i1 = he > 0 ? he - 1 : 0, i0 = hs > 0 ? hs - 1 : 0;
            int j1 = we > 0 ? we - 1 : 0, j0 = ws > 0 ? ws - 1 : 0;
            float v11 = B[i1 * SROW + j1];
            float v01 = B[i0 * SROW + j1];
            float v10 = B[i1 * SROW + j0];
            float v00 = B[i0 * SROW + j0];
            float t11 = (he > 0 && we > 0) ? v11 : 0.0f;
            float t01 = (hs > 0 && we > 0) ? v01 : 0.0f;
            float t10 = (he > 0 && ws > 0) ? v10 : 0.0f;
            float t00 = (hs > 0 && ws > 0) ? v00 : 0.0f;
            float bin_sum = ((t11 - t01) - t10) + t00;   // ref op order

            int area = (he - hs) * (we - ws);
            out[(size_t)r * C_ + c] = (area > 0) ? bin_sum / (float)area : 0.0f;
        }
        // no barrier needed here: next iteration writes S[(k+1)&1], and
        // the last reader of that buffer (pool of plane k-1) is separated
        // from the write by this iteration's three barriers.
    }
}

// ---- fallback: R11 direct-sum kernel (ws too small) ----
__global__ __launch_bounds__(256) void psroi_direct_kernel(
    const float* __restrict__ fsam,
    const float* __restrict__ box,
    float* __restrict__ out)
{
    int id = blockIdx.x;
    int j  = id & 7;
    int m  = id >> 3;
    int g  = (m < 512) ? j : j + 8;
    int l  = (m < 512) ? m : m - 512;
    int c    = g * 16 + (l >> 5);
    int rblk = l & 31;
    if (c >= C_) return;

    int r = rblk * 256 + (int)threadIdx.x;
    int pw = c % P_;
    int ph = (c / P_) % P_;

    const float* bx = box + (size_t)r * 5;
    int   b  = (int)bx[0];
    float x1 = rintf(bx[1]);
    float y1 = rintf(bx[2]);
    float x2 = rintf(bx[3] + 1.0f);
    float y2 = rintf(bx[4] + 1.0f);

    float roi_w = fmaxf(x2 - x1, 0.1f);
    float roi_h = fmaxf(y2 - y1, 0.1f);

    const float RCP7 = __uint_as_float(0x3E124925u);
    float bin_w = roi_w * RCP7;
    float bin_h = roi_h * RCP7;
    asm volatile("" : "+v"(bin_w), "+v"(bin_h));

    float hs_f = floorf(sep_ma((float)ph,       bin_h, y1));
    float he_f = ceilf (sep_ma((float)(ph + 1), bin_h, y1));
    float ws_f = floorf(sep_ma((float)pw,       bin_w, x1));
    float we_f = ceilf (sep_ma((float)(pw + 1), bin_w, x1));

    int hs = (int)fminf(fmaxf(hs_f, 0.0f), 80.0f);
    int he = (int)fminf(fmaxf(he_f, 0.0f), 80.0f);
    int ws = (int)fminf(fmaxf(ws_f, 0.0f), 80.0f);
    int we = (int)fminf(fmaxf(we_f, 0.0f), 80.0f);

    const float* plane = fsam + ((size_t)b * C_ + c) * (H_ * W_);
    float s = 0.0f;
    for (int y = hs; y < he; ++y) {
        const float* row = plane + y * W_;
        for (int x = ws; x < we; ++x) s += row[x];
    }
    int area = (he - hs) * (we - ws);
    out[(size_t)r * C_ + c] = (area > 0) ? s / (float)area : 0.0f;
}

extern "C" void kernel_launch(void* const* d_in, const int* in_sizes, int n_in,
                              void* d_out, int out_size, void* d_ws, size_t ws_size,
                              hipStream_t stream) {
    const float* fsam = (const float*)d_in[0];
    const float* box  = (const float*)d_in[1];
    float* out = (float*)d_out;

    // ws layout: [0,32) counts (8 ints), [32, 32+8*8192*4) buckets
    size_t need = 32 + (size_t)N_ * R_ * sizeof(int);   // 262176 B
    if (ws_size >= need) {
        int* cnt     = (int*)d_ws;
        int* buckets = (int*)((char*)d_ws + 32);
        bucket_kernel<<<N_, 256, 0, stream>>>(box, cnt, buckets);
        fused_kernel<<<8 * 92, 512, 0, stream>>>(fsam, box, cnt, buckets, out);
    } else {
        psroi_direct_kernel<<<8192, 256, 0, stream>>>(fsam, box, out);
    }
}

// Round 21
// 35.160 us; speedup vs baseline: 1.1015x; 1.0049x over previous
//
#include <hip/hip_runtime.h>

// PSROI pooling: fsam (N=8, C=245, H=80, W=80) f32, box (R=8192, 5) f32
// out (R, 245) f32. out[r, c] = mean over fsam[b, c, hs:he, ws:we].
//
// ARITHMETIC (frozen since R10, DO NOT TOUCH): bin = roi * fl32(1/7)
// (reciprocal multiply, 0x3E124925) and edges = SEPARATELY-rounded
// g*bin + off (asm barriers). Matches ref (absmax <= 0.016 << 0.0725).
//
// R20: persistent multi-plane blocks + LDS double-buffer pipeline.
// R15-R19 plateau at ~37-39us while the throughput model says ~10us ->
// latency exposure: phase-lockstep blocks (load|scan|scan|pool separated
// by barriers) at 2.3 blocks/CU effective residency. Now: grid 736 =
// 8 images x 92; block owns 2-3 planes of one image (c = s, s+92, s+184);
// LDS 2x26.9KB (3 blocks/CU, 24 waves); plane k+1's 1600 float4 are
// loaded into REGISTERS right after plane k's first barrier (latency
// hides under k's scans+pool) and ds_written into the other buffer.
// Buffer parity => no extra barrier (3 barriers/plane). Scan + pool +
// bucket + edge arithmetic copied verbatim -> bit-identical output.

#define N_ 8
#define C_ 245
#define H_ 80
#define W_ 80
#define R_ 8192
#define P_ 7
#define SROW 84                    // row stride in floats (21 float4)
#define PLF4 1680                  // float4s per plane buffer (80*21)

// XLA-style separately-rounded a*b + c in f32; barriers forbid contraction.
__device__ __forceinline__ float sep_ma(float a, float b, float c) {
    float p = a * b;                 // v_mul_f32, IEEE RN
    asm volatile("" : "+v"(p));      // contraction barrier
    float s = p + c;                 // v_add_f32, IEEE RN
    asm volatile("" : "+v"(s));
    return s;
}

// ---- kernel 1: deterministic bucket build (8 blocks, no atomics) ----
__global__ __launch_bounds__(256) void bucket_kernel(
    const float* __restrict__ box, int* __restrict__ cnt,
    int* __restrict__ buckets)
{
    __shared__ int psum[256];
    int b = blockIdx.x;                    // image
    int t = threadIdx.x;
    int r0 = t * 32;                       // contiguous range per thread

    unsigned match = 0u;
    int m = 0;
    #pragma unroll
    for (int k = 0; k < 32; ++k) {
        int bb = (int)box[(size_t)(r0 + k) * 5];
        if (bb == b) { match |= 1u << k; ++m; }
    }
    psum[t] = m;
    __syncthreads();

    for (int off = 1; off < 256; off <<= 1) {
        int v = (t >= off) ? psum[t - off] : 0;
        __syncthreads();
        psum[t] += v;
        __syncthreads();
    }
    int pos = psum[t] - m;                 // exclusive prefix
    for (int k = 0; k < 32; ++k)
        if (match & (1u << k)) buckets[b * R_ + pos++] = r0 + k;
    if (t == 255) cnt[b] = psum[255];
}

__device__ __forceinline__ float4 f4_add(float4 a, float4 b) {
    return make_float4(a.x + b.x, a.y + b.y, a.z + b.z, a.w + b.w);
}

// ---- kernel 2: persistent dual-buffer SAT + pool, 512 threads ----
__global__ __launch_bounds__(512) void fused_kernel(
    const float* __restrict__ fsam,
    const float* __restrict__ box,
    const int* __restrict__ cnt,
    const int* __restrict__ buckets,
    float* __restrict__ out)
{
    __shared__ float S[2][H_ * SROW];      // 2 x 26880 B = 53760 B
    int id  = blockIdx.x;                  // 0..735
    int b   = id & 7;                      // image (XCD swizzle: XCD = b)
    int s   = id >> 3;                     // 0..91
    int np  = (s <= 60) ? 3 : 2;           // planes: c = s, s+92, s+184
    int tid = threadIdx.x;

    int n  = cnt[b];
    const int* lst = buckets + b * R_;

    // register staging for one plane (1600 float4 / 512 threads)
    float4 ld0, ld1, ld2, ld3;
    auto do_load = [&](int c) {
        const float4* src = (const float4*)(fsam + ((size_t)b * C_ + c) * (H_ * W_));
        ld0 = src[tid];
        ld1 = src[tid + 512];
        ld2 = src[tid + 1024];
        if (tid < 64) ld3 = src[tid + 1536];
    };
    auto wr1 = [&](float* B, int i, float4 v) {
        int row = (int)((unsigned)i / 20u);
        int c4  = i - row * 20;
        ((float4*)B)[row * 21 + c4] = v;
    };
    auto do_write = [&](float* B) {
        wr1(B, tid,        ld0);
        wr1(B, tid +  512, ld1);
        wr1(B, tid + 1024, ld2);
        if (tid < 64) wr1(B, tid + 1536, ld3);
    };

    do_load(s);                            // prologue: plane 0

    for (int k = 0; k < np; ++k) {
        int c = s + 92 * k;
        float* B = S[k & 1];

        do_write(B);
        __syncthreads();                   // raw plane ready in B

        if (k + 1 < np) do_load(s + 92 * (k + 1));   // hides under scans+pool

        // ---- horizontal scan: 80 rows x 4 chunks of 20, in registers ----
        if (tid < 320) {
            int row = tid >> 2, q = tid & 3;
            float4* base = (float4*)B + row * 21 + q * 5;
            float v[20];
            #pragma unroll
            for (int kk = 0; kk < 5; ++kk) {
                float4 t = base[kk];
                v[4*kk+0] = t.x; v[4*kk+1] = t.y; v[4*kk+2] = t.z; v[4*kk+3] = t.w;
            }
            float run = 0.0f;
            #pragma unroll
            for (int j = 0; j < 20; ++j) { run += v[j]; v[j] = run; }
            float incl = run;
            #pragma unroll
            for (int d = 1; d < 4; d <<= 1) {
                float u = __shfl_up(incl, d, 4);
                if (q >= d) incl += u;
            }
            float off = incl - run;
            #pragma unroll
            for (int j = 0; j < 20; ++j) v[j] += off;
            #pragma unroll
            for (int kk = 0; kk < 5; ++kk)
                base[kk] = make_float4(v[4*kk+0], v[4*kk+1], v[4*kk+2], v[4*kk+3]);
        }
        __syncthreads();

        // ---- vertical scan: 20 col-groups x 16 chunks of 5 rows ----
        if (tid < 320) {
            int cg = tid >> 4;             // 0..19
            int ch = tid & 15;             // 0..15
            float4* col = (float4*)B + cg;
            float4 v[5];
            float4 run = make_float4(0.f, 0.f, 0.f, 0.f);
            #pragma unroll
            for (int j = 0; j < 5; ++j) {
                run = f4_add(run, col[(ch * 5 + j) * 21]);
                v[j] = run;
            }
            float4 incl = run;
            #pragma unroll
            for (int d = 1; d < 16; d <<= 1) {
                float4 u;
                u.x = __shfl_up(incl.x, d, 16);
                u.y = __shfl_up(incl.y, d, 16);
                u.z = __shfl_up(incl.z, d, 16);
                u.w = __shfl_up(incl.w, d, 16);
                if (ch >= d) incl = f4_add(incl, u);
            }
            float4 off = make_float4(incl.x - run.x, incl.y - run.y,
                                     incl.z - run.z, incl.w - run.w);
            #pragma unroll
            for (int j = 0; j < 5; ++j)
                col[(ch * 5 + j) * 21] = f4_add(v[j], off);
        }
        __syncthreads();

        // ---- pool this image's ROIs from SAT in B ----
        int ph = (c / P_) % P_;            // block-uniform
        int pw = c % P_;

        for (int i = tid; i < n; i += 512) {
            int r = lst[i];
            const float* bx = box + (size_t)r * 5;

            // ---- R10-frozen edge arithmetic ----
            float x1 = rintf(bx[1]);
            float y1 = rintf(bx[2]);
            float x2 = rintf(bx[3] + 1.0f);
            float y2 = rintf(bx[4] + 1.0f);

            float roi_w = fmaxf(x2 - x1, 0.1f);
            float roi_h = fmaxf(y2 - y1, 0.1f);

            const float RCP7 = __uint_as_float(0x3E124925u); // fl32(1/7)
            float bin_w = roi_w * RCP7;
            float bin_h = roi_h * RCP7;
            asm volatile("" : "+v"(bin_w), "+v"(bin_h));

            float hs_f = floorf(sep_ma((float)ph,       bin_h, y1));
            float he_f = ceilf (sep_ma((float)(ph + 1), bin_h, y1));
            float ws_f = floorf(sep_ma((float)pw,       bin_w, x1));
            float we_f = ceilf (sep_ma((float)(pw + 1), bin_w, x1));

            int hs = (int)fminf(fmaxf(hs_f, 0.0f), 80.0f);
            int he = (int)fminf(fmaxf(he_f, 0.0f), 80.0f);
            int ws = (int)fminf(fmaxf(ws_f, 0.0f), 80.0f);
            int we = (int)fminf(fmaxf(we_f, 0.0f), 80.0f);

            // SAT taps with implicit zero row/col (clamp + select)
            int i1 = he > 0 ? he - 1 : 0, i0 = hs > 0 ? hs - 1 : 0;
            int j1 = we > 0 ? we - 1 : 0, j0 = ws > 0 ? ws - 1 : 0;
            float v11 = B[i1 * SROW + j1];
            float v01 = B[i0 * SROW + j1];
            float v10 = B[i1 * SROW + j0];
            float v00 = B[i0 * SROW + j0];
            float t11 = (he > 0 && we > 0) ? v11 : 0.0f;
            float t01 = (hs > 0 && we > 0) ? v01 : 0.0f;
            float t10 = (he > 0 && ws > 0) ? v10 : 0.0f;
            float t00 = (hs > 0 && ws > 0) ? v00 : 0.0f;
            float bin_sum = ((t11 - t01) - t10) + t00;   // ref op order

            int area = (he - hs) * (we - ws);
            out[(size_t)r * C_ + c] = (area > 0) ? bin_sum / (float)area : 0.0f;
        }
        // no barrier needed here: next iteration writes S[(k+1)&1], and
        // the last reader of that buffer (pool of plane k-1) is separated
        // from the write by this iteration's three barriers.
    }
}

// ---- fallback: R11 direct-sum kernel (ws too small) ----
__global__ __launch_bounds__(256) void psroi_direct_kernel(
    const float* __restrict__ fsam,
    const float* __restrict__ box,
    float* __restrict__ out)
{
    int id = blockIdx.x;
    int j  = id & 7;
    int m  = id >> 3;
    int g  = (m < 512) ? j : j + 8;
    int l  = (m < 512) ? m : m - 512;
    int c    = g * 16 + (l >> 5);
    int rblk = l & 31;
    if (c >= C_) return;

    int r = rblk * 256 + (int)threadIdx.x;
    int pw = c % P_;
    int ph = (c / P_) % P_;

    const float* bx = box + (size_t)r * 5;
    int   b  = (int)bx[0];
    float x1 = rintf(bx[1]);
    float y1 = rintf(bx[2]);
    float x2 = rintf(bx[3] + 1.0f);
    float y2 = rintf(bx[4] + 1.0f);

    float roi_w = fmaxf(x2 - x1, 0.1f);
    float roi_h = fmaxf(y2 - y1, 0.1f);

    const float RCP7 = __uint_as_float(0x3E124925u);
    float bin_w = roi_w * RCP7;
    float bin_h = roi_h * RCP7;
    asm volatile("" : "+v"(bin_w), "+v"(bin_h));

    float hs_f = floorf(sep_ma((float)ph,       bin_h, y1));
    float he_f = ceilf (sep_ma((float)(ph + 1), bin_h, y1));
    float ws_f = floorf(sep_ma((float)pw,       bin_w, x1));
    float we_f = ceilf (sep_ma((float)(pw + 1), bin_w, x1));

    int hs = (int)fminf(fmaxf(hs_f, 0.0f), 80.0f);
    int he = (int)fminf(fmaxf(he_f, 0.0f), 80.0f);
    int ws = (int)fminf(fmaxf(ws_f, 0.0f), 80.0f);
    int we = (int)fminf(fmaxf(we_f, 0.0f), 80.0f);

    const float* plane = fsam + ((size_t)b * C_ + c) * (H_ * W_);
    float s = 0.0f;
    for (int y = hs; y < he; ++y) {
        const float* row = plane + y * W_;
        for (int x = ws; x < we; ++x) s += row[x];
    }
    int area = (he - hs) * (we - ws);
    out[(size_t)r * C_ + c] = (area > 0) ? s / (float)area : 0.0f;
}

extern "C" void kernel_launch(void* const* d_in, const int* in_sizes, int n_in,
                              void* d_out, int out_size, void* d_ws, size_t ws_size,
                              hipStream_t stream) {
    const float* fsam = (const float*)d_in[0];
    const float* box  = (const float*)d_in[1];
    float* out = (float*)d_out;

    // ws layout: [0,32) counts (8 ints), [32, 32+8*8192*4) buckets
    size_t need = 32 + (size_t)N_ * R_ * sizeof(int);   // 262176 B
    if (ws_size >= need) {
        int* cnt     = (int*)d_ws;
        int* buckets = (int*)((char*)d_ws + 32);
        bucket_kernel<<<N_, 256, 0, stream>>>(box, cnt, buckets);
        fused_kernel<<<8 * 92, 512, 0, stream>>>(fsam, box, cnt, buckets, out);
    } else {
        psroi_direct_kernel<<<8192, 256, 0, stream>>>(fsam, box, out);
    }
}